// Round 1
// baseline (7653.735 us; speedup 1.0000x reference)
//
#include <hip/hip_runtime.h>

#define NODES 20000
#define NEDGE 600000
#define BATCH 128
#define ITERS 120
#define LEAK  0.01f

// ---------------- preprocessing kernels ----------------

__global__ void zero_counts_kernel(int* counts) {
    int i = blockIdx.x * blockDim.x + threadIdx.x;
    if (i < NODES) counts[i] = 0;
}

__global__ void count_kernel(const int* __restrict__ tgt, int* counts) {
    int e = blockIdx.x * blockDim.x + threadIdx.x;
    if (e < NEDGE) atomicAdd(&counts[tgt[e]], 1);
}

// single-block exclusive scan over NODES counts -> row_off (NODES+1), cursor copy
__global__ void scan_kernel(const int* __restrict__ counts, int* row_off, int* cursor) {
    __shared__ int sums[1024];
    const int CH = (NODES + 1023) / 1024;  // 20
    int tid = threadIdx.x;
    int base = tid * CH;
    int s = 0;
    for (int i = 0; i < CH; ++i) {
        int idx = base + i;
        if (idx < NODES) s += counts[idx];
    }
    sums[tid] = s;
    __syncthreads();
    // Hillis-Steele inclusive scan
    for (int off = 1; off < 1024; off <<= 1) {
        int v = sums[tid];
        int add = (tid >= off) ? sums[tid - off] : 0;
        __syncthreads();
        sums[tid] = v + add;
        __syncthreads();
    }
    int running = (tid == 0) ? 0 : sums[tid - 1];
    for (int i = 0; i < CH; ++i) {
        int idx = base + i;
        if (idx < NODES) {
            row_off[idx] = running;
            cursor[idx]  = running;
            running += counts[idx];
        }
    }
    if (tid == 1023) row_off[NODES] = running;  // == NEDGE
}

__global__ void scatter_kernel(const int* __restrict__ tgt, const int* __restrict__ src,
                               const float* __restrict__ w,
                               int* cursor, float* csr_w, int* csr_src) {
    int e = blockIdx.x * blockDim.x + threadIdx.x;
    if (e < NEDGE) {
        int p = atomicAdd(&cursor[tgt[e]], 1);
        csr_w[p]   = w[e];
        csr_src[p] = src[e];
    }
}

// bIn[t][b] = x[b][t] + bias[t]; xhat1[t][b] = leaky(bIn)   (absorbs iteration 1)
// LDS-tiled transpose: x is [BATCH][NODES] row-major.
__global__ void init_kernel(const float* __restrict__ x, const float* __restrict__ bias,
                            float* __restrict__ bIn, float* __restrict__ xhat) {
    __shared__ float tile[32][33];
    int tt = blockIdx.x * 32;   // node tile base
    int bb = blockIdx.y * 32;   // batch tile base
    int tx = threadIdx.x, ty = threadIdx.y;
    // read x[b][t], coalesced along t
    for (int i = ty; i < 32; i += 8)
        tile[i][tx] = x[(bb + i) * NODES + tt + tx];
    __syncthreads();
    // write bIn[t][b], coalesced along b
    for (int i = ty; i < 32; i += 8) {
        int t = tt + i;
        float v = tile[tx][t - tt] + bias[t];
        bIn[t * BATCH + bb + tx]  = v;
        xhat[t * BATCH + bb + tx] = (v < 0.0f) ? LEAK * v : v;
    }
}

// ---------------- main iteration kernel ----------------
// one block (128 threads) per node; thread b handles batch column b
__global__ __launch_bounds__(BATCH) void spmv_act_kernel(
        const float* __restrict__ xin, const float* __restrict__ bIn,
        const float* __restrict__ csr_w, const int* __restrict__ csr_src,
        const int* __restrict__ row_off, float* __restrict__ xout) {
    int t = blockIdx.x;
    int b = threadIdx.x;
    float acc = bIn[t * BATCH + b];
    int beg = row_off[t];
    int end = row_off[t + 1];
    for (int e = beg; e < end; ++e) {
        float w = csr_w[e];
        int   s = csr_src[e];
        acc = fmaf(w, xin[s * BATCH + b], acc);
    }
    xout[t * BATCH + b] = (acc < 0.0f) ? LEAK * acc : acc;
}

// out[b][t] = xin[t][b], LDS-tiled
__global__ void transpose_out_kernel(const float* __restrict__ xin, float* __restrict__ out) {
    __shared__ float tile[32][33];
    int tt = blockIdx.x * 32;
    int bb = blockIdx.y * 32;
    int tx = threadIdx.x, ty = threadIdx.y;
    // read xin[t][b], coalesced along b
    for (int i = ty; i < 32; i += 8)
        tile[i][tx] = xin[(tt + i) * BATCH + bb + tx];   // tile[t_local][b_local]
    __syncthreads();
    // write out[b][t], coalesced along t
    for (int i = ty; i < 32; i += 8)
        out[(bb + i) * NODES + tt + tx] = tile[tx][i];
}

// ---------------- launch ----------------

extern "C" void kernel_launch(void* const* d_in, const int* in_sizes, int n_in,
                              void* d_out, int out_size, void* d_ws, size_t ws_size,
                              hipStream_t stream) {
    const float* x        = (const float*)d_in[0];   // [BATCH, NODES]
    const float* weights  = (const float*)d_in[1];   // [NEDGE]
    const float* bias     = (const float*)d_in[2];   // [NODES]
    const int*   tgt      = (const int*)d_in[3];     // [NEDGE]
    const int*   src      = (const int*)d_in[4];     // [NEDGE]
    float* out = (float*)d_out;                      // [BATCH, NODES]

    // workspace layout
    char* ws = (char*)d_ws;
    size_t off = 0;
    float* bIn     = (float*)(ws + off); off += (size_t)NODES * BATCH * sizeof(float);
    float* xA      = (float*)(ws + off); off += (size_t)NODES * BATCH * sizeof(float);
    float* xB      = (float*)(ws + off); off += (size_t)NODES * BATCH * sizeof(float);
    float* csr_w   = (float*)(ws + off); off += (size_t)NEDGE * sizeof(float);
    int*   csr_src = (int*)  (ws + off); off += (size_t)NEDGE * sizeof(int);
    int*   counts  = (int*)  (ws + off); off += (size_t)NODES * sizeof(int);
    int*   row_off = (int*)  (ws + off); off += (size_t)(NODES + 1) * sizeof(int);
    int*   cursor  = (int*)  (ws + off); off += (size_t)NODES * sizeof(int);

    // --- build CSR (by target) ---
    zero_counts_kernel<<<(NODES + 255) / 256, 256, 0, stream>>>(counts);
    count_kernel<<<(NEDGE + 255) / 256, 256, 0, stream>>>(tgt, counts);
    scan_kernel<<<1, 1024, 0, stream>>>(counts, row_off, cursor);
    scatter_kernel<<<(NEDGE + 255) / 256, 256, 0, stream>>>(tgt, src, weights,
                                                            cursor, csr_w, csr_src);

    // --- bIn + first iteration ---
    init_kernel<<<dim3(NODES / 32, BATCH / 32), dim3(32, 8), 0, stream>>>(x, bias, bIn, xA);

    // --- remaining 119 iterations, ping-pong ---
    float* cur = xA;
    float* nxt = xB;
    for (int it = 1; it < ITERS; ++it) {
        spmv_act_kernel<<<NODES, BATCH, 0, stream>>>(cur, bIn, csr_w, csr_src, row_off, nxt);
        float* tmp = cur; cur = nxt; nxt = tmp;
    }

    // --- transpose to [BATCH, NODES] ---
    transpose_out_kernel<<<dim3(NODES / 32, BATCH / 32), dim3(32, 8), 0, stream>>>(cur, out);
}

// Round 2
// 4235.968 us; speedup vs baseline: 1.8068x; 1.8068x over previous
//
#include <hip/hip_runtime.h>

#define NODES 20000
#define NEDGE 600000
#define BATCH 128
#define ITERS 120
#define LEAK  0.01f

// padded CSR capacity: each row rounds up to multiple of 4 (max +3/row)
#define NEDGE_PAD (NEDGE + 4 * NODES)

// ---------------- preprocessing kernels ----------------

__global__ void zero_counts_kernel(int* counts, int2* csr_edge) {
    int i = blockIdx.x * blockDim.x + threadIdx.x;
    if (i < NODES) counts[i] = 0;
    // zero the padded edge array so pad slots contribute w=0 * xhat[0]
    for (int j = i; j < NEDGE_PAD; j += gridDim.x * blockDim.x)
        csr_edge[j] = make_int2(0, 0);
}

__global__ void count_kernel(const int* __restrict__ tgt, int* counts) {
    int e = blockIdx.x * blockDim.x + threadIdx.x;
    if (e < NEDGE) atomicAdd(&counts[tgt[e]], 1);
}

// single-block exclusive scan over padded counts -> row_off (NODES+1), cursor copy
__global__ void scan_kernel(const int* __restrict__ counts, int* row_off, int* cursor) {
    __shared__ int sums[1024];
    const int CH = (NODES + 1023) / 1024;  // 20
    int tid = threadIdx.x;
    int base = tid * CH;
    int s = 0;
    for (int i = 0; i < CH; ++i) {
        int idx = base + i;
        if (idx < NODES) s += (counts[idx] + 3) & ~3;   // padded length
    }
    sums[tid] = s;
    __syncthreads();
    for (int off = 1; off < 1024; off <<= 1) {
        int v = sums[tid];
        int add = (tid >= off) ? sums[tid - off] : 0;
        __syncthreads();
        sums[tid] = v + add;
        __syncthreads();
    }
    int running = (tid == 0) ? 0 : sums[tid - 1];
    for (int i = 0; i < CH; ++i) {
        int idx = base + i;
        if (idx < NODES) {
            row_off[idx] = running;
            cursor[idx]  = running;
            running += (counts[idx] + 3) & ~3;
        }
    }
    if (tid == 1023) row_off[NODES] = running;
}

// scatter edges into padded CSR; pack (src*64, weight-bits) into one int2
__global__ void scatter_kernel(const int* __restrict__ tgt, const int* __restrict__ src,
                               const float* __restrict__ w,
                               int* cursor, int2* csr_edge) {
    int e = blockIdx.x * blockDim.x + threadIdx.x;
    if (e < NEDGE) {
        int p = atomicAdd(&cursor[tgt[e]], 1);
        csr_edge[p] = make_int2(src[e] * 64, __float_as_int(w[e]));
    }
}

// bIn[t][b] = x[b][t] + bias[t]; xhat1[t][b] = leaky(bIn)   (absorbs iteration 1)
__global__ void init_kernel(const float* __restrict__ x, const float* __restrict__ bias,
                            float* __restrict__ bIn, float* __restrict__ xhat) {
    __shared__ float tile[32][33];
    int tt = blockIdx.x * 32;
    int bb = blockIdx.y * 32;
    int tx = threadIdx.x, ty = threadIdx.y;
    for (int i = ty; i < 32; i += 8)
        tile[i][tx] = x[(bb + i) * NODES + tt + tx];
    __syncthreads();
    for (int i = ty; i < 32; i += 8) {
        int t = tt + i;
        float v = tile[tx][i] + bias[t];
        bIn[t * BATCH + bb + tx]  = v;
        xhat[t * BATCH + bb + tx] = (v < 0.0f) ? LEAK * v : v;
    }
}

// ---------------- main iteration kernel ----------------
// one wave (64 lanes) per node; lane l holds batch columns {2l, 2l+1} as float2.
// rows are padded to multiples of 4 -> branch-free 4-edge chunks, 4 gathers in flight.
__global__ __launch_bounds__(256) void spmv_act_kernel(
        const float2* __restrict__ xin2, const float2* __restrict__ bIn2,
        const int2* __restrict__ csr_edge, const int* __restrict__ row_off,
        float2* __restrict__ xout2) {
    int wave = threadIdx.x >> 6;
    int lane = threadIdx.x & 63;
    int t = __builtin_amdgcn_readfirstlane(blockIdx.x * 4 + wave);

    float2 acc = bIn2[t * 64 + lane];
    int beg = row_off[t];
    int end = row_off[t + 1];
    for (int e = beg; e < end; e += 4) {
        int2 e0 = csr_edge[e + 0];
        int2 e1 = csr_edge[e + 1];
        int2 e2 = csr_edge[e + 2];
        int2 e3 = csr_edge[e + 3];
        float2 v0 = xin2[e0.x + lane];
        float2 v1 = xin2[e1.x + lane];
        float2 v2 = xin2[e2.x + lane];
        float2 v3 = xin2[e3.x + lane];
        float w0 = __int_as_float(e0.y);
        float w1 = __int_as_float(e1.y);
        float w2 = __int_as_float(e2.y);
        float w3 = __int_as_float(e3.y);
        acc.x = fmaf(w0, v0.x, acc.x); acc.y = fmaf(w0, v0.y, acc.y);
        acc.x = fmaf(w1, v1.x, acc.x); acc.y = fmaf(w1, v1.y, acc.y);
        acc.x = fmaf(w2, v2.x, acc.x); acc.y = fmaf(w2, v2.y, acc.y);
        acc.x = fmaf(w3, v3.x, acc.x); acc.y = fmaf(w3, v3.y, acc.y);
    }
    float2 r;
    r.x = (acc.x < 0.0f) ? LEAK * acc.x : acc.x;
    r.y = (acc.y < 0.0f) ? LEAK * acc.y : acc.y;
    xout2[t * 64 + lane] = r;
}

// out[b][t] = xin[t][b], LDS-tiled
__global__ void transpose_out_kernel(const float* __restrict__ xin, float* __restrict__ out) {
    __shared__ float tile[32][33];
    int tt = blockIdx.x * 32;
    int bb = blockIdx.y * 32;
    int tx = threadIdx.x, ty = threadIdx.y;
    for (int i = ty; i < 32; i += 8)
        tile[i][tx] = xin[(tt + i) * BATCH + bb + tx];
    __syncthreads();
    for (int i = ty; i < 32; i += 8)
        out[(bb + i) * NODES + tt + tx] = tile[tx][i];
}

// ---------------- launch ----------------

extern "C" void kernel_launch(void* const* d_in, const int* in_sizes, int n_in,
                              void* d_out, int out_size, void* d_ws, size_t ws_size,
                              hipStream_t stream) {
    const float* x        = (const float*)d_in[0];   // [BATCH, NODES]
    const float* weights  = (const float*)d_in[1];   // [NEDGE]
    const float* bias     = (const float*)d_in[2];   // [NODES]
    const int*   tgt      = (const int*)d_in[3];     // [NEDGE]
    const int*   src      = (const int*)d_in[4];     // [NEDGE]
    float* out = (float*)d_out;                      // [BATCH, NODES]

    char* ws = (char*)d_ws;
    size_t off = 0;
    float* bIn      = (float*)(ws + off); off += (size_t)NODES * BATCH * sizeof(float);
    float* xA       = (float*)(ws + off); off += (size_t)NODES * BATCH * sizeof(float);
    float* xB       = (float*)(ws + off); off += (size_t)NODES * BATCH * sizeof(float);
    int2*  csr_edge = (int2*) (ws + off); off += (size_t)NEDGE_PAD * sizeof(int2);
    int*   counts   = (int*)  (ws + off); off += (size_t)NODES * sizeof(int);
    int*   row_off  = (int*)  (ws + off); off += (size_t)(NODES + 1) * sizeof(int);
    int*   cursor   = (int*)  (ws + off); off += (size_t)NODES * sizeof(int);

    // --- build padded CSR (by target) ---
    zero_counts_kernel<<<(NODES + 255) / 256, 256, 0, stream>>>(counts, csr_edge);
    count_kernel<<<(NEDGE + 255) / 256, 256, 0, stream>>>(tgt, counts);
    scan_kernel<<<1, 1024, 0, stream>>>(counts, row_off, cursor);
    scatter_kernel<<<(NEDGE + 255) / 256, 256, 0, stream>>>(tgt, src, weights,
                                                            cursor, csr_edge);

    // --- bIn + first iteration ---
    init_kernel<<<dim3(NODES / 32, BATCH / 32), dim3(32, 8), 0, stream>>>(x, bias, bIn, xA);

    // --- remaining 119 iterations, ping-pong ---
    float* cur = xA;
    float* nxt = xB;
    for (int it = 1; it < ITERS; ++it) {
        spmv_act_kernel<<<NODES / 4, 256, 0, stream>>>(
            (const float2*)cur, (const float2*)bIn, csr_edge, row_off, (float2*)nxt);
        float* tmp = cur; cur = nxt; nxt = tmp;
    }

    // --- transpose to [BATCH, NODES] ---
    transpose_out_kernel<<<dim3(NODES / 32, BATCH / 32), dim3(32, 8), 0, stream>>>(cur, out);
}

// Round 3
// 2209.458 us; speedup vs baseline: 3.4641x; 1.9172x over previous
//
#include <hip/hip_runtime.h>

#define NODES 20000
#define NEDGE 600000
#define BATCH 128
#define ITERS 120
#define LEAK  0.01f

// padded CSR capacity: each row rounds up to multiple of 8 (max +7/row)
#define NEDGE_PAD (NEDGE + 8 * NODES)

typedef unsigned int uint32;

// ---- bf16 pack/unpack helpers (RNE) ----
__device__ __forceinline__ uint32 rne_bf16_bits(float f) {
    uint32 u = __float_as_uint(f);
    u += 0x7fffu + ((u >> 16) & 1u);
    return u >> 16;
}
__device__ __forceinline__ uint32 pack_bf16x2(float lo, float hi) {
    return (rne_bf16_bits(hi) << 16) | rne_bf16_bits(lo);
}
__device__ __forceinline__ float unpack_lo(uint32 u) { return __uint_as_float(u << 16); }
__device__ __forceinline__ float unpack_hi(uint32 u) { return __uint_as_float(u & 0xffff0000u); }

// ---------------- preprocessing kernels ----------------

__global__ void zero_counts_kernel(int* counts, int2* csr_edge) {
    int i = blockIdx.x * blockDim.x + threadIdx.x;
    if (i < NODES) counts[i] = 0;
    for (int j = i; j < NEDGE_PAD; j += gridDim.x * blockDim.x)
        csr_edge[j] = make_int2(0, 0);   // pad: w=0, src=0
}

__global__ void count_kernel(const int* __restrict__ tgt, int* counts) {
    int e = blockIdx.x * blockDim.x + threadIdx.x;
    if (e < NEDGE) atomicAdd(&counts[tgt[e]], 1);
}

// single-block exclusive scan over 8-padded counts -> row_off (NODES+1), cursor copy
__global__ void scan_kernel(const int* __restrict__ counts, int* row_off, int* cursor) {
    __shared__ int sums[1024];
    const int CH = (NODES + 1023) / 1024;  // 20
    int tid = threadIdx.x;
    int base = tid * CH;
    int s = 0;
    for (int i = 0; i < CH; ++i) {
        int idx = base + i;
        if (idx < NODES) s += (counts[idx] + 7) & ~7;
    }
    sums[tid] = s;
    __syncthreads();
    for (int off = 1; off < 1024; off <<= 1) {
        int v = sums[tid];
        int add = (tid >= off) ? sums[tid - off] : 0;
        __syncthreads();
        sums[tid] = v + add;
        __syncthreads();
    }
    int running = (tid == 0) ? 0 : sums[tid - 1];
    for (int i = 0; i < CH; ++i) {
        int idx = base + i;
        if (idx < NODES) {
            row_off[idx] = running;
            cursor[idx]  = running;
            running += (counts[idx] + 7) & ~7;
        }
    }
    if (tid == 1023) row_off[NODES] = running;
}

// scatter edges into padded CSR; pack (src*64, weight-bits) into one int2
__global__ void scatter_kernel(const int* __restrict__ tgt, const int* __restrict__ src,
                               const float* __restrict__ w,
                               int* cursor, int2* csr_edge) {
    int e = blockIdx.x * blockDim.x + threadIdx.x;
    if (e < NEDGE) {
        int p = atomicAdd(&cursor[tgt[e]], 1);
        csr_edge[p] = make_int2(src[e] * 64, __float_as_int(w[e]));
    }
}

// bIn[t][b] = x[b][t] + bias[t]   (fp32, layout t*128+b) via LDS-tiled transpose
__global__ void init_bin_kernel(const float* __restrict__ x, const float* __restrict__ bias,
                                float* __restrict__ bIn) {
    __shared__ float tile[32][33];
    int tt = blockIdx.x * 32;
    int bb = blockIdx.y * 32;
    int tx = threadIdx.x, ty = threadIdx.y;
    for (int i = ty; i < 32; i += 8)
        tile[i][tx] = x[(bb + i) * NODES + tt + tx];
    __syncthreads();
    for (int i = ty; i < 32; i += 8) {
        int t = tt + i;
        bIn[t * BATCH + bb + tx] = tile[tx][i] + bias[t];
    }
}

// xhat1 = pack_bf16(leaky(bIn))  (absorbs iteration 1; xhat0 = 0)
__global__ void init_xhat_kernel(const float2* __restrict__ bIn2, uint32* __restrict__ xhat) {
    int idx = blockIdx.x * blockDim.x + threadIdx.x;   // over NODES*64
    float2 v = bIn2[idx];
    float a = (v.x < 0.0f) ? LEAK * v.x : v.x;
    float b = (v.y < 0.0f) ? LEAK * v.y : v.y;
    xhat[idx] = pack_bf16x2(a, b);
}

// ---------------- main iteration kernel ----------------
// one wave per node; lane l holds batch cols {2l, 2l+1} packed as bf16x2 in one uint.
// rows padded to multiples of 8 -> branch-free 8-edge chunks, 8 gathers in flight;
// the 8 edge loads are wave-uniform contiguous 64 B -> scalar-load friendly.
__global__ __launch_bounds__(256) void spmv_act_kernel(
        const uint32* __restrict__ xin, const float2* __restrict__ bIn2,
        const int2* __restrict__ csr_edge, const int* __restrict__ row_off,
        uint32* __restrict__ xout) {
    int wave = threadIdx.x >> 6;
    int lane = threadIdx.x & 63;
    int t = __builtin_amdgcn_readfirstlane(blockIdx.x * 4 + wave);

    float2 acc = bIn2[t * 64 + lane];
    int beg = row_off[t];
    int end = row_off[t + 1];
    for (int e = beg; e < end; e += 8) {
        int2 E[8];
        uint32 U[8];
#pragma unroll
        for (int i = 0; i < 8; ++i) E[i] = csr_edge[e + i];
#pragma unroll
        for (int i = 0; i < 8; ++i) U[i] = xin[E[i].x + lane];
#pragma unroll
        for (int i = 0; i < 8; ++i) {
            float w = __int_as_float(E[i].y);
            acc.x = fmaf(w, unpack_lo(U[i]), acc.x);
            acc.y = fmaf(w, unpack_hi(U[i]), acc.y);
        }
    }
    float rx = (acc.x < 0.0f) ? LEAK * acc.x : acc.x;
    float ry = (acc.y < 0.0f) ? LEAK * acc.y : acc.y;
    xout[t * 64 + lane] = pack_bf16x2(rx, ry);
}

// out[b][t] = unpack(xin_packed[t][b/2], b&1), LDS-tiled; 32-node tiles, full batch
__global__ __launch_bounds__(256) void transpose_out_kernel(
        const uint32* __restrict__ xin, float* __restrict__ out) {
    __shared__ uint32 tile[32][65];
    int tt = blockIdx.x * 32;
    int tid = threadIdx.x;
    // phase 1: coalesced read of 32 nodes x 64 uints
    {
        int u = tid & 63;
        int n0 = tid >> 6;           // 0..3
        for (int n = n0; n < 32; n += 4)
            tile[n][u] = xin[(tt + n) * 64 + u];
    }
    __syncthreads();
    // phase 2: write out[b][tt+tn], coalesced along tn (32 floats per row-segment)
    {
        int tn = tid & 31;
        int b0 = tid >> 5;           // 0..7
        for (int b = b0; b < BATCH; b += 8) {
            uint32 u = tile[tn][b >> 1];
            float v = (b & 1) ? unpack_hi(u) : unpack_lo(u);
            out[(size_t)b * NODES + tt + tn] = v;
        }
    }
}

// ---------------- launch ----------------

extern "C" void kernel_launch(void* const* d_in, const int* in_sizes, int n_in,
                              void* d_out, int out_size, void* d_ws, size_t ws_size,
                              hipStream_t stream) {
    const float* x        = (const float*)d_in[0];   // [BATCH, NODES]
    const float* weights  = (const float*)d_in[1];   // [NEDGE]
    const float* bias     = (const float*)d_in[2];   // [NODES]
    const int*   tgt      = (const int*)d_in[3];     // [NEDGE]
    const int*   src      = (const int*)d_in[4];     // [NEDGE]
    float* out = (float*)d_out;                      // [BATCH, NODES]

    char* ws = (char*)d_ws;
    size_t off = 0;
    float*  bIn      = (float*) (ws + off); off += (size_t)NODES * BATCH * sizeof(float);
    uint32* xA       = (uint32*)(ws + off); off += (size_t)NODES * 64 * sizeof(uint32);
    uint32* xB       = (uint32*)(ws + off); off += (size_t)NODES * 64 * sizeof(uint32);
    int2*   csr_edge = (int2*)  (ws + off); off += (size_t)NEDGE_PAD * sizeof(int2);
    int*    counts   = (int*)   (ws + off); off += (size_t)NODES * sizeof(int);
    int*    row_off  = (int*)   (ws + off); off += (size_t)(NODES + 1) * sizeof(int);
    int*    cursor   = (int*)   (ws + off); off += (size_t)NODES * sizeof(int);

    // --- build padded CSR (by target) ---
    zero_counts_kernel<<<(NODES + 255) / 256, 256, 0, stream>>>(counts, csr_edge);
    count_kernel<<<(NEDGE + 255) / 256, 256, 0, stream>>>(tgt, counts);
    scan_kernel<<<1, 1024, 0, stream>>>(counts, row_off, cursor);
    scatter_kernel<<<(NEDGE + 255) / 256, 256, 0, stream>>>(tgt, src, weights,
                                                            cursor, csr_edge);

    // --- bIn + first iteration ---
    init_bin_kernel<<<dim3(NODES / 32, BATCH / 32), dim3(32, 8), 0, stream>>>(x, bias, bIn);
    init_xhat_kernel<<<NODES * 64 / 256, 256, 0, stream>>>((const float2*)bIn, xA);

    // --- remaining 119 iterations, ping-pong ---
    uint32* cur = xA;
    uint32* nxt = xB;
    for (int it = 1; it < ITERS; ++it) {
        spmv_act_kernel<<<NODES / 4, 256, 0, stream>>>(
            cur, (const float2*)bIn, csr_edge, row_off, nxt);
        uint32* tmp = cur; cur = nxt; nxt = tmp;
    }

    // --- transpose to [BATCH, NODES] fp32 ---
    transpose_out_kernel<<<NODES / 32, 256, 0, stream>>>(cur, out);
}